// Round 1
// baseline (184.677 us; speedup 1.0000x reference)
//
#include <hip/hip_runtime.h>

// Problem constants (match reference)
#define BB 32
#define KK 128
#define SS 48
#define LL 2
#define HH 128
#define AA 500

static constexpr float NEG_INF = -1e30f;

// Output layout (flat float32, concatenated in return order)
static constexpr long SZ_BK    = (long)BB * KK;                 // 4096
static constexpr long SZ_HID   = (long)BB * KK * SS * LL * HH;  // 50331648
static constexpr long SZ_TREE  = (long)BB * KK * SS * HH;       // 25165824
static constexpr long SZ_ACT   = (long)BB * KK * AA;            // 2048000

static constexpr long OFF_GEN   = 0;
static constexpr long OFF_DISC  = OFF_GEN  + SZ_BK;
static constexpr long OFF_HID   = OFF_DISC + SZ_BK;
static constexpr long OFF_CELL  = OFF_HID  + SZ_HID;
static constexpr long OFF_TREE  = OFF_CELL + SZ_HID;
static constexpr long OFF_WID   = OFF_TREE + SZ_TREE;
static constexpr long OFF_NCONS = OFF_WID  + BB;
static constexpr long OFF_NOPEN = OFF_NCONS + SZ_BK;
static constexpr long OFF_ACT   = OFF_NOPEN + SZ_BK;
static constexpr long OFF_APOS  = OFF_ACT  + SZ_ACT;
static constexpr long OFF_PTR   = OFF_APOS + SZ_BK;
// total = OFF_PTR + SZ_BK = 127901728

// One block per batch row: stable descending sort of masked gen_ll (K=128),
// write permutation + all small sorted outputs.
__global__ void sort_small_kernel(
    const float* __restrict__ gen_ll,
    const float* __restrict__ disc_ll,
    const int*   __restrict__ beam_widths,
    const int*   __restrict__ ncons,
    const int*   __restrict__ nopen,
    const int*   __restrict__ actions_pos,
    const int*   __restrict__ pointer,
    const int*   __restrict__ size_ptr,
    float*       __restrict__ out,
    int*         __restrict__ perm_ws)
{
    const int b = blockIdx.x;
    const int i = threadIdx.x;  // 0..127

    __shared__ float mv[KK];
    __shared__ int   perm[KK];

    const int bw = beam_widths[b];
    float v = gen_ll[b * KK + i];
    if (i >= bw) v = NEG_INF;
    mv[i] = v;
    __syncthreads();

    // stable descending rank: elements strictly greater, or equal with lower idx
    int rank = 0;
#pragma unroll 8
    for (int j = 0; j < KK; ++j) {
        float vj = mv[j];
        rank += (vj > v) || (vj == v && j < i);
    }
    perm[rank] = i;
    __syncthreads();

    const int src = perm[i];
    perm_ws[b * KK + i] = src;

    out[OFF_GEN   + b * KK + i] = mv[src];
    out[OFF_DISC  + b * KK + i] = disc_ll[b * KK + src];
    out[OFF_NCONS + b * KK + i] = (float)ncons[b * KK + src];
    out[OFF_NOPEN + b * KK + i] = (float)nopen[b * KK + src];
    out[OFF_APOS  + b * KK + i] = (float)actions_pos[b * KK + src];
    out[OFF_PTR   + b * KK + i] = (float)pointer[b * KK + src];

    if (i == 0) {
        int sz = size_ptr[0];
        out[OFF_WID + b] = (float)(bw < sz ? bw : sz);
    }
}

// Vectorized beam-gather: out[(b,k), r] = in[(b, perm[b,k]), r], float4 lanes.
__global__ void gather_f4(const float4* __restrict__ in,
                          float4*       __restrict__ out,
                          const int*    __restrict__ perm,
                          int inner4, int total4)
{
    int g = blockIdx.x * blockDim.x + threadIdx.x;
    if (g >= total4) return;
    int bk = g / inner4;          // b*K + k
    int r  = g - bk * inner4;
    int b  = bk >> 7;             // K = 128
    int src = perm[bk];
    out[g] = in[(b * KK + src) * inner4 + r];
}

// Actions gather: int4 -> float4 (write ints as floats). inner4 = 500/4 = 125.
__global__ void gather_actions(const int4* __restrict__ in,
                               float4*     __restrict__ out,
                               const int*  __restrict__ perm)
{
    const int total4 = BB * KK * (AA / 4);  // 512000
    int g = blockIdx.x * blockDim.x + threadIdx.x;
    if (g >= total4) return;
    const int inner4 = AA / 4;  // 125
    int bk = g / inner4;
    int r  = g - bk * inner4;
    int b  = bk >> 7;
    int src = perm[bk];
    int4 a = in[(b * KK + src) * inner4 + r];
    out[g] = make_float4((float)a.x, (float)a.y, (float)a.z, (float)a.w);
}

extern "C" void kernel_launch(void* const* d_in, const int* in_sizes, int n_in,
                              void* d_out, int out_size, void* d_ws, size_t ws_size,
                              hipStream_t stream) {
    const float* gen_ll      = (const float*)d_in[0];
    const float* disc_ll     = (const float*)d_in[1];
    const float* hiddens     = (const float*)d_in[2];
    const float* cells       = (const float*)d_in[3];
    const float* trees       = (const float*)d_in[4];
    const int*   beam_widths = (const int*)d_in[5];
    const int*   ncons       = (const int*)d_in[6];
    const int*   nopen       = (const int*)d_in[7];
    const int*   actions     = (const int*)d_in[8];
    const int*   actions_pos = (const int*)d_in[9];
    const int*   pointer     = (const int*)d_in[10];
    const int*   size_ptr    = (const int*)d_in[11];

    float* out = (float*)d_out;
    int*   perm_ws = (int*)d_ws;  // B*K ints

    // 1) sort + small outputs + permutation
    sort_small_kernel<<<BB, KK, 0, stream>>>(
        gen_ll, disc_ll, beam_widths, ncons, nopen, actions_pos, pointer,
        size_ptr, out, perm_ws);

    // 2) big gathers (float4-vectorized)
    const int block = 256;

    {   // hiddens: inner = S*L*H = 12288 floats -> 3072 float4
        const int inner4 = SS * LL * HH / 4;          // 3072
        const int total4 = (int)(SZ_HID / 4);         // 12582912
        gather_f4<<<(total4 + block - 1) / block, block, 0, stream>>>(
            (const float4*)hiddens, (float4*)(out + OFF_HID), perm_ws, inner4, total4);
    }
    {   // cells
        const int inner4 = SS * LL * HH / 4;
        const int total4 = (int)(SZ_HID / 4);
        gather_f4<<<(total4 + block - 1) / block, block, 0, stream>>>(
            (const float4*)cells, (float4*)(out + OFF_CELL), perm_ws, inner4, total4);
    }
    {   // trees: inner = S*H = 6144 floats -> 1536 float4
        const int inner4 = SS * HH / 4;               // 1536
        const int total4 = (int)(SZ_TREE / 4);        // 6291456
        gather_f4<<<(total4 + block - 1) / block, block, 0, stream>>>(
            (const float4*)trees, (float4*)(out + OFF_TREE), perm_ws, inner4, total4);
    }
    {   // actions: int -> float
        const int total4 = BB * KK * (AA / 4);        // 512000
        gather_actions<<<(total4 + block - 1) / block, block, 0, stream>>>(
            (const int4*)actions, (float4*)(out + OFF_ACT), perm_ws);
    }
}

// Round 2
// 171.680 us; speedup vs baseline: 1.0757x; 1.0757x over previous
//
#include <hip/hip_runtime.h>

// Problem constants (match reference)
#define BB 32
#define KK 128
#define SS 48
#define LL 2
#define HH 128
#define AA 500

static constexpr float NEG_INF = -1e30f;

// Output layout (flat float32, concatenated in return order)
static constexpr long SZ_BK    = (long)BB * KK;                 // 4096
static constexpr long SZ_HID   = (long)BB * KK * SS * LL * HH;  // 50331648
static constexpr long SZ_TREE  = (long)BB * KK * SS * HH;       // 25165824
static constexpr long SZ_ACT   = (long)BB * KK * AA;            // 2048000

static constexpr long OFF_GEN   = 0;
static constexpr long OFF_DISC  = OFF_GEN  + SZ_BK;
static constexpr long OFF_HID   = OFF_DISC + SZ_BK;
static constexpr long OFF_CELL  = OFF_HID  + SZ_HID;
static constexpr long OFF_TREE  = OFF_CELL + SZ_HID;
static constexpr long OFF_WID   = OFF_TREE + SZ_TREE;
static constexpr long OFF_NCONS = OFF_WID  + BB;
static constexpr long OFF_NOPEN = OFF_NCONS + SZ_BK;
static constexpr long OFF_ACT   = OFF_NOPEN + SZ_BK;
static constexpr long OFF_APOS  = OFF_ACT  + SZ_ACT;
static constexpr long OFF_PTR   = OFF_APOS + SZ_BK;
// total = OFF_PTR + SZ_BK = 127901728 floats

typedef float f32x4 __attribute__((ext_vector_type(4)));
typedef int   i32x4 __attribute__((ext_vector_type(4)));

// One block per batch row: stable descending sort of masked gen_ll (K=128),
// write permutation + all small sorted outputs.
__global__ void sort_small_kernel(
    const float* __restrict__ gen_ll,
    const float* __restrict__ disc_ll,
    const int*   __restrict__ beam_widths,
    const int*   __restrict__ ncons,
    const int*   __restrict__ nopen,
    const int*   __restrict__ actions_pos,
    const int*   __restrict__ pointer,
    const int*   __restrict__ size_ptr,
    float*       __restrict__ out,
    int*         __restrict__ perm_ws)
{
    const int b = blockIdx.x;
    const int i = threadIdx.x;  // 0..127

    __shared__ float mv[KK];
    __shared__ int   perm[KK];

    const int bw = beam_widths[b];
    float v = gen_ll[b * KK + i];
    if (i >= bw) v = NEG_INF;
    mv[i] = v;
    __syncthreads();

    // stable descending rank: strictly greater, or equal with lower index
    int rank = 0;
#pragma unroll 8
    for (int j = 0; j < KK; ++j) {
        float vj = mv[j];
        rank += (vj > v) || (vj == v && j < i);
    }
    perm[rank] = i;
    __syncthreads();

    const int src = perm[i];
    perm_ws[b * KK + i] = src;

    out[OFF_GEN   + b * KK + i] = mv[src];
    out[OFF_DISC  + b * KK + i] = disc_ll[b * KK + src];
    out[OFF_NCONS + b * KK + i] = (float)ncons[b * KK + src];
    out[OFF_NOPEN + b * KK + i] = (float)nopen[b * KK + src];
    out[OFF_APOS  + b * KK + i] = (float)actions_pos[b * KK + src];
    out[OFF_PTR   + b * KK + i] = (float)pointer[b * KK + src];

    if (i == 0) {
        int sz = size_ptr[0];
        out[OFF_WID + b] = (float)(bw < sz ? bw : sz);
    }
}

// Fused, division-free gather of all beam-indexed big arrays.
// grid = (31, B*K). blockIdx.y = bk (dst row), blockIdx.x = chunk:
//   0..11  -> hiddens  (inner 3072 float4, 12 chunks of 256)
//   12..23 -> cells
//   24..29 -> trees    (inner 1536 float4, 6 chunks of 256)
//   30     -> actions  (125 int4 -> float4)
// All data is touched exactly once (perm is a per-batch bijection) ->
// nontemporal loads/stores to keep the stream out of L2.
__global__ __launch_bounds__(256) void gather_fused(
    const f32x4* __restrict__ hiddens,
    const f32x4* __restrict__ cells,
    const f32x4* __restrict__ trees,
    const i32x4* __restrict__ actions,
    const int*   __restrict__ perm,
    float*       __restrict__ out)
{
    const int bk  = blockIdx.y;          // 0..4095
    const int c   = blockIdx.x;          // 0..30
    const int tid = threadIdx.x;         // 0..255
    const int b   = bk >> 7;             // K = 128
    const int src = perm[bk];            // scalar (wave-uniform) load
    const int srow = b * KK + src;       // source row index

    if (c < 24) {
        // hiddens (c<12) or cells (c>=12): inner4 = 3072
        const bool is_h = c < 12;
        const int cc = is_h ? c : c - 12;
        const f32x4* in = is_h ? hiddens : cells;
        f32x4* o = (f32x4*)(out + (is_h ? OFF_HID : OFF_CELL));
        const int r = cc * 256 + tid;                  // 0..3071
        f32x4 v = __builtin_nontemporal_load(&in[(long)srow * 3072 + r]);
        __builtin_nontemporal_store(v, &o[(long)bk * 3072 + r]);
    } else if (c < 30) {
        // trees: inner4 = 1536
        const int r = (c - 24) * 256 + tid;            // 0..1535
        f32x4 v = __builtin_nontemporal_load(&trees[(long)srow * 1536 + r]);
        f32x4* o = (f32x4*)(out + OFF_TREE);
        __builtin_nontemporal_store(v, &o[(long)bk * 1536 + r]);
    } else {
        // actions: inner4 = 125 (int -> float)
        if (tid < 125) {
            i32x4 a = __builtin_nontemporal_load(&actions[(long)srow * 125 + tid]);
            f32x4 v;
            v.x = (float)a.x; v.y = (float)a.y; v.z = (float)a.z; v.w = (float)a.w;
            f32x4* o = (f32x4*)(out + OFF_ACT);
            __builtin_nontemporal_store(v, &o[(long)bk * 125 + tid]);
        }
    }
}

extern "C" void kernel_launch(void* const* d_in, const int* in_sizes, int n_in,
                              void* d_out, int out_size, void* d_ws, size_t ws_size,
                              hipStream_t stream) {
    const float* gen_ll      = (const float*)d_in[0];
    const float* disc_ll     = (const float*)d_in[1];
    const float* hiddens     = (const float*)d_in[2];
    const float* cells       = (const float*)d_in[3];
    const float* trees       = (const float*)d_in[4];
    const int*   beam_widths = (const int*)d_in[5];
    const int*   ncons       = (const int*)d_in[6];
    const int*   nopen       = (const int*)d_in[7];
    const int*   actions     = (const int*)d_in[8];
    const int*   actions_pos = (const int*)d_in[9];
    const int*   pointer     = (const int*)d_in[10];
    const int*   size_ptr    = (const int*)d_in[11];

    float* out = (float*)d_out;
    int*   perm_ws = (int*)d_ws;  // B*K ints

    // 1) sort + small outputs + permutation
    sort_small_kernel<<<BB, KK, 0, stream>>>(
        gen_ll, disc_ll, beam_widths, ncons, nopen, actions_pos, pointer,
        size_ptr, out, perm_ws);

    // 2) single fused gather for all big arrays
    dim3 grid(31, BB * KK);
    gather_fused<<<grid, 256, 0, stream>>>(
        (const f32x4*)hiddens, (const f32x4*)cells, (const f32x4*)trees,
        (const i32x4*)actions, perm_ws, out);
}